// Round 14
// baseline (1900.000 us; speedup 1.0000x reference)
//
#include <hip/hip_runtime.h>

#define S_LEN 2048
#define DIN   50
#define H     64
#define ROWS  16
#define XSTR  (S_LEN * DIN)   // per-batch-row x stride (floats)

typedef short bf16x8 __attribute__((ext_vector_type(8)));   // MFMA A/B operand (8 bf16)
typedef float f32x4  __attribute__((ext_vector_type(4)));   // MFMA C/D (4 f32)

union U8 { bf16x8 v; unsigned u[4]; };

// pack 2 f32 -> 1 u32 of 2 bf16 (RNE), guide T12 recipe (no builtin on gfx950)
__device__ __forceinline__ unsigned cvt2bf(float lo, float hi) {
    unsigned r;
    asm("v_cvt_pk_bf16_f32 %0, %1, %2" : "=v"(r) : "v"(lo), "v"(hi));
    return r;
}

__device__ __forceinline__ bf16x8 pack8v(float4 a, float4 b) {
    U8 u;
    u.u[0] = cvt2bf(a.x, a.y); u.u[1] = cvt2bf(a.z, a.w);
    u.u[2] = cvt2bf(b.x, b.y); u.u[3] = cvt2bf(b.z, b.w);
    return u.v;
}

__device__ __forceinline__ bf16x8 pack8a(const float f[8]) {
    U8 u;
    u.u[0] = cvt2bf(f[0], f[1]); u.u[1] = cvt2bf(f[2], f[3]);
    u.u[2] = cvt2bf(f[4], f[5]); u.u[3] = cvt2bf(f[6], f[7]);
    return u.v;
}

// tanh(v) = 1 - 2/(exp(2v)+1); ~1e-6 rel err, exact at +/-inf
__device__ __forceinline__ float tanh_fast(float v) {
    float e = __builtin_amdgcn_exp2f(v * 2.885390082f);
    return 1.0f - 2.0f * __builtin_amdgcn_rcpf(e + 1.0f);
}

// sum over the four 16-lane groups (proven R3..R13, absmax 0)
__device__ __forceinline__ float red4(float v) {
#if __has_builtin(__builtin_amdgcn_permlane16_swap) && __has_builtin(__builtin_amdgcn_permlane32_swap)
    typedef unsigned u2 __attribute__((ext_vector_type(2)));
    u2 r = __builtin_amdgcn_permlane16_swap(__float_as_uint(v), __float_as_uint(v), false, false);
    float s = __uint_as_float(r[0]) + __uint_as_float(r[1]);
    u2 q = __builtin_amdgcn_permlane32_swap(__float_as_uint(s), __float_as_uint(s), false, false);
    return __uint_as_float(q[0]) + __uint_as_float(q[1]);
#else
    v += __shfl_xor(v, 16, 64);
    v += __shfl_xor(v, 32, 64);
    return v;
#endif
}

// B-fragment: lane holds B[k][n]: n = 16*nt + (lane&15), k = 32*kf + (lane>>4)*8 + j
__device__ __forceinline__ bf16x8 load_bfrag(const float* __restrict__ W, int ld, int kmax,
                                             int n, int ks) {
    float f[8];
    #pragma unroll
    for (int j = 0; j < 8; ++j)
        f[j] = (ks + j < kmax) ? W[n * ld + ks + j] : 0.0f;
    return pack8a(f);
}

#define MFMA(a, b, c) __builtin_amdgcn_mfma_f32_16x16x32_bf16(a, b, c, 0, 0, 0)

__global__ __launch_bounds__(64)
__attribute__((amdgpu_waves_per_eu(1, 1)))   // 1 wave/SIMD: full 512-VGPR budget
void rnn_mfma(const float* __restrict__ x,
              const float* __restrict__ W_ih0, const float* __restrict__ W_hh0,
              const float* __restrict__ b_ih0, const float* __restrict__ b_hh0,
              const float* __restrict__ W_ih1, const float* __restrict__ W_hh1,
              const float* __restrict__ b_ih1, const float* __restrict__ b_hh1,
              const float* __restrict__ W1, const float* __restrict__ b1,
              const float* __restrict__ W2, const float* __restrict__ b2,
              float* __restrict__ out)
{
    const int blk  = blockIdx.x;          // owns batch rows [16*blk, 16*blk+16)
    const int lane = threadIdx.x & 63;
    const int li   = lane & 15;           // A/C row index r (and B/C col n within tile)
    const int lg   = lane >> 4;           // k-group / C row-group

    // f32 h staging for the bf16 A-fragment re-layout (row-pad 68: 2-way banks)
    __shared__ __align__(16) float hb1[ROWS][68];
    __shared__ __align__(16) float hb2[ROWS][68];

    // ---- static B-fragments: 4 matrices x 4 N-tiles x 2 K-frags ----
    bf16x8 whh0B[4][2], wih1B[4][2], whh1B[4][2], wih0B[4][2];
    f32x4  b0c[4], b1c[4];
    #pragma unroll
    for (int nt = 0; nt < 4; ++nt) {
        const int n = 16 * nt + li;
        #pragma unroll
        for (int kf = 0; kf < 2; ++kf) {
            const int ks = 32 * kf + lg * 8;
            whh0B[nt][kf] = load_bfrag(W_hh0, H,   H,   n, ks);
            wih1B[nt][kf] = load_bfrag(W_ih1, H,   H,   n, ks);
            whh1B[nt][kf] = load_bfrag(W_hh1, H,   H,   n, ks);
            wih0B[nt][kf] = load_bfrag(W_ih0, DIN, DIN, n, ks);   // k>=50 -> 0
        }
        const float v0 = b_ih0[n] + b_hh0[n];
        const float v1 = b_ih1[n] + b_hh1[n];
        b0c[nt] = f32x4{v0, v0, v0, v0};
        b1c[nt] = f32x4{v1, v1, v1, v1};
    }

    // per-lane x base: row = 16*blk + li, k-offset lg*8 folded in
    const float* __restrict__ xbase = x + (size_t)(ROWS * blk + li) * XSTR + lg * 8;

    float xr0[8], xr1[8];     // raw f32 of x[t+2] (frag0 k=lg*8.., frag1 +32)
    bf16x8 xfragA[2];         // bf16 A-frags of x[t+1]
    bf16x8 h1frag[2] = {bf16x8{0,0,0,0,0,0,0,0}, bf16x8{0,0,0,0,0,0,0,0}};
    bf16x8 h2frag[2] = {bf16x8{0,0,0,0,0,0,0,0}, bf16x8{0,0,0,0,0,0,0,0}};
    f32x4  xpacc[4];

    // ---- prologue: xp[0] via MFMA; xfragA = x[1]; xr = raw x[2] ----
    {
        float f0[8], f1[8];
        #pragma unroll
        for (int m = 0; m < 4; ++m) {                 // x[0]
            float2 a = *(const float2*)(xbase + 2 * m);
            f0[2*m] = a.x; f0[2*m+1] = a.y;
            float2 b = *(const float2*)(xbase + 32 + 2 * m);
            f1[2*m] = b.x; f1[2*m+1] = b.y;
        }
        bf16x8 x0f0 = pack8a(f0), x0f1 = pack8a(f1);
        #pragma unroll
        for (int nt = 0; nt < 4; ++nt) {
            xpacc[nt] = MFMA(x0f0, wih0B[nt][0], b0c[nt]);
            xpacc[nt] = MFMA(x0f1, wih0B[nt][1], xpacc[nt]);
        }
        #pragma unroll
        for (int m = 0; m < 4; ++m) {                 // x[1]
            float2 a = *(const float2*)(xbase + 50 + 2 * m);
            f0[2*m] = a.x; f0[2*m+1] = a.y;
            float2 b = *(const float2*)(xbase + 50 + 32 + 2 * m);
            f1[2*m] = b.x; f1[2*m+1] = b.y;
        }
        xfragA[0] = pack8a(f0); xfragA[1] = pack8a(f1);
        #pragma unroll
        for (int m = 0; m < 4; ++m) {                 // raw x[2]
            float2 a = *(const float2*)(xbase + 100 + 2 * m);
            xr0[2*m] = a.x; xr0[2*m+1] = a.y;
            float2 b = *(const float2*)(xbase + 100 + 32 + 2 * m);
            xr1[2*m] = b.x; xr1[2*m+1] = b.y;
        }
    }

    float xn0[8], xn1[8];     // landing regs for x[t+3] loads
    #pragma unroll
    for (int j = 0; j < 8; ++j) { xn0[j] = 0.0f; xn1[j] = 0.0f; }

    #pragma unroll 2
    for (int t = 0; t < S_LEN; ++t) {
        // (a) whh1 . h2[t-1] early (h2frag ready at step start), C-init = bias1
        f32x4 acc2[4];
        #pragma unroll
        for (int nt = 0; nt < 4; ++nt) {
            acc2[nt] = MFMA(h2frag[0], whh1B[nt][0], b1c[nt]);
            acc2[nt] = MFMA(h2frag[1], whh1B[nt][1], acc2[nt]);
        }
        // (b) stage 1: acc1 = xp[t] + Whh0 . h1[t-1]
        f32x4 acc1[4];
        #pragma unroll
        for (int nt = 0; nt < 4; ++nt) {
            acc1[nt] = MFMA(h1frag[0], whh0B[nt][0], xpacc[nt]);
            acc1[nt] = MFMA(h1frag[1], whh0B[nt][1], acc1[nt]);
        }
        // (c) xp[t+1] from xfragA = x[t+1]
        #pragma unroll
        for (int nt = 0; nt < 4; ++nt) {
            xpacc[nt] = MFMA(xfragA[0], wih0B[nt][0], b0c[nt]);
            xpacc[nt] = MFMA(xfragA[1], wih0B[nt][1], xpacc[nt]);
        }
        // (d) issue x[t+3] loads (in-bounds for t+3 <= 2046; guarded at 2047)
        const int t3 = t + 3;
        if (t3 <= S_LEN - 2) {
            const float* p = xbase + t3 * DIN;
            #pragma unroll
            for (int m = 0; m < 4; ++m) {
                float2 a = *(const float2*)(p + 2 * m);
                xn0[2*m] = a.x; xn0[2*m+1] = a.y;
                float2 b = *(const float2*)(p + 32 + 2 * m);
                xn1[2*m] = b.x; xn1[2*m+1] = b.y;
            }
        } else if (t3 == S_LEN - 1) {
            const float* p = xbase + t3 * DIN;
            #pragma unroll
            for (int m = 0; m < 4; ++m) {            // frag0: k <= 31, in-bounds
                float2 a = *(const float2*)(p + 2 * m);
                xn0[2*m] = a.x; xn0[2*m+1] = a.y;
            }
            #pragma unroll
            for (int j = 0; j < 8; ++j) {            // frag1: guard k >= 50
                const int k = 32 + lg * 8 + j;
                xn1[j] = (k < DIN) ? p[32 + j] : 0.0f;
            }
        }
        // (e) tanh1 -> hb1 (f32, C/D layout)
        #pragma unroll
        for (int nt = 0; nt < 4; ++nt)
            #pragma unroll
            for (int i = 0; i < 4; ++i)
                hb1[lg * 4 + i][16 * nt + li] = tanh_fast(acc1[nt][i]);
        // (f) re-read h1[t] as A-frags (same-wave LDS RAW: lgkmcnt only)
        {
            float4 a0 = *(const float4*)&hb1[li][lg * 8];
            float4 a1 = *(const float4*)&hb1[li][lg * 8 + 4];
            float4 c0 = *(const float4*)&hb1[li][32 + lg * 8];
            float4 c1 = *(const float4*)&hb1[li][32 + lg * 8 + 4];
            h1frag[0] = pack8v(a0, a1);
            h1frag[1] = pack8v(c0, c1);
        }
        // (g) stage 2 finish: acc2 += Wih1 . h1[t]
        #pragma unroll
        for (int nt = 0; nt < 4; ++nt) {
            acc2[nt] = MFMA(h1frag[0], wih1B[nt][0], acc2[nt]);
            acc2[nt] = MFMA(h1frag[1], wih1B[nt][1], acc2[nt]);
        }
        // (h) tanh2 -> hb2 -> h2frag
        #pragma unroll
        for (int nt = 0; nt < 4; ++nt)
            #pragma unroll
            for (int i = 0; i < 4; ++i)
                hb2[lg * 4 + i][16 * nt + li] = tanh_fast(acc2[nt][i]);
        {
            float4 a0 = *(const float4*)&hb2[li][lg * 8];
            float4 a1 = *(const float4*)&hb2[li][lg * 8 + 4];
            float4 c0 = *(const float4*)&hb2[li][32 + lg * 8];
            float4 c1 = *(const float4*)&hb2[li][32 + lg * 8 + 4];
            h2frag[0] = pack8v(a0, a1);
            h2frag[1] = pack8v(c0, c1);
        }
        // (i) rotate x pipeline: xfragA = bf16(x[t+2]); xr <- xn
        {
            float q0[8], q1[8];
            #pragma unroll
            for (int j = 0; j < 8; ++j) { q0[j] = xr0[j]; q1[j] = xr1[j]; }
            xfragA[0] = pack8a(q0);
            xfragA[1] = pack8a(q1);
            #pragma unroll
            for (int j = 0; j < 8; ++j) { xr0[j] = xn0[j]; xr1[j] = xn1[j]; }
        }
    }

    // ---- head (f32 h2[2047] lives in hb2): relu(W1.h2+b1) -> sigmoid(W2.+b2) ----
    {
        const int r = li, qg = lg;
        float part = 0.0f;
        #pragma unroll
        for (int jj = 0; jj < 8; ++jj) {
            const int q = 8 * qg + jj;
            float a = b1[q];
            const float4* w4 = (const float4*)(W1 + q * H);
            #pragma unroll
            for (int kq = 0; kq < 16; ++kq) {
                float4 wv = w4[kq];
                a = fmaf(hb2[r][4*kq+0], wv.x, a);
                a = fmaf(hb2[r][4*kq+1], wv.y, a);
                a = fmaf(hb2[r][4*kq+2], wv.z, a);
                a = fmaf(hb2[r][4*kq+3], wv.w, a);
            }
            part = fmaf(fmaxf(a, 0.0f), W2[q], part);
        }
        float tot = red4(part);
        if (lane < ROWS)
            out[ROWS * blk + lane] = 1.0f / (1.0f + __expf(-(tot + b2[0])));
    }
}

extern "C" void kernel_launch(void* const* d_in, const int* in_sizes, int n_in,
                              void* d_out, int out_size, void* d_ws, size_t ws_size,
                              hipStream_t stream) {
    const float* x     = (const float*)d_in[0];
    const float* W_ih0 = (const float*)d_in[1];
    const float* W_hh0 = (const float*)d_in[2];
    const float* b_ih0 = (const float*)d_in[3];
    const float* b_hh0 = (const float*)d_in[4];
    const float* W_ih1 = (const float*)d_in[5];
    const float* W_hh1 = (const float*)d_in[6];
    const float* b_ih1 = (const float*)d_in[7];
    const float* b_hh1 = (const float*)d_in[8];
    const float* W1    = (const float*)d_in[9];
    const float* b1    = (const float*)d_in[10];
    const float* W2    = (const float*)d_in[11];
    const float* b2    = (const float*)d_in[12];
    float* out = (float*)d_out;

    rnn_mfma<<<dim3(512 / ROWS), dim3(64), 0, stream>>>(
        x, W_ih0, W_hh0, b_ih0, b_hh0,
        W_ih1, W_hh1, b_ih1, b_hh1,
        W1, b1, W2, b2, out);
}